// Round 12
// baseline (1542.797 us; speedup 1.0000x reference)
//
#include <hip/hip_runtime.h>

typedef __bf16 bf16x8 __attribute__((ext_vector_type(8)));
typedef float f32x4 __attribute__((ext_vector_type(4)));
typedef unsigned short ushort_t;
typedef unsigned short u16x8 __attribute__((ext_vector_type(8)));

#define BSZ 4096
#define HID 1024
#define INPD 512
#define NSPAN 8
#define NOUT 2
#define NDAYS 20
#define XLD 1536  // X = [inp(512) | h(1024)] K-dim

// Frag-order layout: element (row, k) of a [R][K] bf16 matrix lives at
//   ((row>>4)*(K/32) + (k>>5))*512 + ((k&31)>>3)*128 + (row&15)*8 + (k&7)
// each 16x32 MFMA fragment is 1KB contiguous = exact mfma_16x16x32 operand map.

__device__ __forceinline__ ushort_t f2bf(float f) {
  union { float f; unsigned u; } v; v.f = f;
  unsigned r = v.u + 0x7FFFu + ((v.u >> 16) & 1u);
  return (ushort_t)(r >> 16);
}
__device__ __forceinline__ float bf2f(ushort_t b) {
  union { unsigned u; float f; } v; v.u = ((unsigned)b) << 16;
  return v.f;
}
__device__ __forceinline__ float sigf(float x) { return 1.f / (1.f + __expf(-x)); }
__device__ __forceinline__ float tanhfast(float x) { return 2.f / (1.f + __expf(-2.f * x)) - 1.f; }

__device__ __forceinline__ void gload16(const void* g, void* l) {
  __builtin_amdgcn_global_load_lds((const __attribute__((address_space(1))) void*)g,
                                   (__attribute__((address_space(3))) void*)l, 16, 0, 0);
}

// ---------------------------------------------------------------------------
// Wg prep -> frag-order. Gate-reordered row r_perm = (j/16)*64 + gate*16 + (j%16).
// ---------------------------------------------------------------------------
__global__ void prep_gates_w(const float* __restrict__ Wih, const float* __restrict__ Whh,
                             const float* __restrict__ bih, const float* __restrict__ bhh,
                             ushort_t* __restrict__ Wgf, float* __restrict__ bg) {
  int gid = blockIdx.x * 256 + threadIdx.x;
  int rb = gid / 3072;           // 48*64
  int rem = gid - rb * 3072;
  int kk = rem >> 6;
  int li = rem & 63;
  int rp = rb * 16 + (li & 15);
  int kb = kk * 32 + ((li >> 4) << 3);
  int g = (rp >> 4) & 3;
  int j = (rp >> 6) * 16 + (rp & 15);
  int src = g * HID + j;
  const float* s = (kb < INPD) ? (Wih + (size_t)src * INPD + kb)
                               : (Whh + (size_t)src * HID + (kb - INPD));
  u16x8 o;
#pragma unroll
  for (int e = 0; e < 8; ++e) o[e] = f2bf(s[e]);
  *(u16x8*)(Wgf + (size_t)gid * 8) = o;
  if (kk == 0 && li < 16) bg[rp] = bih[src] + bhh[src];
}

// Wfc2 prep -> frag-order [576][1024]: rows 0..511 = Wfcin, 512..513 = Wfcout,
// 514..575 = 0.  gid over 576*1024/8 = 73728 -> 288 blocks.
__global__ void prep_fcin_w(const float* __restrict__ W, const float* __restrict__ Wout,
                            ushort_t* __restrict__ Wf) {
  int gid = blockIdx.x * 256 + threadIdx.x;
  int rb = gid / 2048;           // 32*64
  int rem = gid - rb * 2048;
  int kk = rem >> 6;
  int li = rem & 63;
  int row = rb * 16 + (li & 15);
  int kb = kk * 32 + ((li >> 4) << 3);
  u16x8 o;
  if (row < 512) {
    const float* s = W + (size_t)row * HID + kb;
#pragma unroll
    for (int e = 0; e < 8; ++e) o[e] = f2bf(s[e]);
  } else if (row < 514) {
    const float* s = Wout + (size_t)(row - 512) * HID + kb;
#pragma unroll
    for (int e = 0; e < 8; ++e) o[e] = f2bf(s[e]);
  } else {
#pragma unroll
    for (int e = 0; e < 8; ++e) o[e] = 0;
  }
  *(u16x8*)(Wf + (size_t)gid * 8) = o;
}

// X init (frag-order): inp part zeros, h part = bf16(hx)
__global__ void init_x(const float* __restrict__ hx, ushort_t* __restrict__ Xf) {
  int gid = blockIdx.x * 256 + threadIdx.x;
  int rb = gid / 3072;
  int rem = gid - rb * 3072;
  int kk = rem >> 6;
  int li = rem & 63;
  int row = rb * 16 + (li & 15);
  int kb = kk * 32 + ((li >> 4) << 3);
  u16x8 o;
  if (kb < INPD) {
#pragma unroll
    for (int e = 0; e < 8; ++e) o[e] = 0;
  } else {
    const float* s = hx + (size_t)row * HID + (kb - INPD);
#pragma unroll
    for (int e = 0; e < 8; ++e) o[e] = f2bf(s[e]);
  }
  *(u16x8*)(Xf + (size_t)gid * 8) = o;
}

// num_spans = softmax(hx @ W_span.T + b_span), fp32
__global__ void span_kernel(const float* __restrict__ hx, const float* __restrict__ Wspan,
                            const float* __restrict__ bspan, float* __restrict__ out) {
  int gid = blockIdx.x * 256 + threadIdx.x;  // over 4096*8
  int b = gid >> 3, o = gid & 7;
  const float4* hr = (const float4*)(hx + (size_t)b * HID);
  const float4* wr = (const float4*)(Wspan + (size_t)o * HID);
  float acc = 0.f;
  for (int i = 0; i < HID / 4; ++i) {
    float4 h = hr[i], w = wr[i];
    acc += h.x * w.x + h.y * w.y + h.z * w.z + h.w * w.w;
  }
  acc += bspan[o];
  float m = acc;
  for (int s = 1; s < 8; s <<= 1) m = fmaxf(m, __shfl_xor(m, s));
  float e = __expf(acc - m);
  float ssum = e;
  for (int s = 1; s < 8; s <<= 1) ssum += __shfl_xor(ssum, s);
  out[gid] = e / ssum;
}

// standalone fcout (only t = NDAYS-1), reads frag-order X
__global__ void fcout_kernel(const ushort_t* __restrict__ Xf, const float* __restrict__ W,
                             const float* __restrict__ bvec, float* __restrict__ outp, int t) {
  const int lane = threadIdx.x & 63;
  const int wave = threadIdx.x >> 6;
  const int b = blockIdx.x * 4 + wave;
  const int rb = b >> 4, r = b & 15;
  const int kk = 16 + (lane >> 1);
  const int ss = (lane & 1) * 2;
  const size_t base = ((size_t)rb * 48 + kk) * 512 + (ss * 16 + r) * 8;
  u16x8 h0 = *(const u16x8*)(Xf + base);
  u16x8 h1 = *(const u16x8*)(Xf + base + 128);
  const float* w0 = W + lane * 16;
  const float* w1 = W + HID + lane * 16;
  float l0 = 0.f, l1 = 0.f;
#pragma unroll
  for (int j = 0; j < 8; ++j) {
    float ha = bf2f(h0[j]);
    l0 += ha * w0[j];
    l1 += ha * w1[j];
    float hb = bf2f(h1[j]);
    l0 += hb * w0[j + 8];
    l1 += hb * w1[j + 8];
  }
#pragma unroll
  for (int s = 32; s > 0; s >>= 1) {
    l0 += __shfl_xor(l0, s);
    l1 += __shfl_xor(l1, s);
  }
  if (lane == 0) {
    l0 += bvec[0];
    l1 += bvec[1];
    float m = fmaxf(l0, l1);
    float e0 = __expf(l0 - m), e1 = __expf(l1 - m);
    float inv = 1.f / (e0 + e1);
    float* o = outp + (size_t)b * (NDAYS * NOUT) + t * NOUT;
    o[0] = e0 * inv;
    o[1] = e1 * inv;
  }
}

// ---------------------------------------------------------------------------
// Gates GEMM v2: 128x128 tile / BK=32 / TWO waves, each wave computes 64x128
// (4 A-frags + 8 B-frags = 12KB LDS read for 32 MFMA -> +37% FLOP/LDS-byte vs
// the 4-wave 64x64 layout; LDS pipe is the CU-level bottleneck).
// Wave 0 stages all 8 A-frags, wave 1 all 8 B-frags (1KB lane-linear each).
// Frag-linear LDS = 0 bank conflicts. Fused LSTM epilogue over 2 gate-groups.
// ---------------------------------------------------------------------------
__global__ __launch_bounds__(128, 2) void gates128_kernel(
    const ushort_t* __restrict__ A, const ushort_t* __restrict__ B,
    const float* __restrict__ bias, float* __restrict__ cbuf,
    ushort_t* __restrict__ hout) {
  __shared__ __align__(16) ushort_t ldsA[8 * 512];
  __shared__ __align__(16) ushort_t ldsB[8 * 512];
  const int tid = threadIdx.x;
  const int lane = tid & 63;
  const int wave = tid >> 6;  // 0..1

  int bid = blockIdx.y * gridDim.x + blockIdx.x;
  int nwg = gridDim.x * gridDim.y;  // 1024, %8==0
  int cpx = nwg >> 3;
  int swz = (bid & 7) * cpx + (bid >> 3);
  int bx = swz % gridDim.x;
  int by = swz / gridDim.x;
  const int bm = bx * 128;
  const int bn = by * 128;
  const int wm = wave * 64;  // this wave's 64-row half

  f32x4 acc[4][8] = {};

  // staging: wave 0 -> A frags 0..7, wave 1 -> B frags 0..7
  const ushort_t* gS = (wave == 0)
      ? (A + ((size_t)(bm >> 4) * 48) * 512 + lane * 8)
      : (B + ((size_t)(bn >> 4) * 48) * 512 + lane * 8);
  ushort_t* lD = (wave == 0) ? ldsA : ldsB;

  for (int kk = 0; kk < 48; ++kk) {
    const size_t ko = (size_t)kk * 512;
#pragma unroll
    for (int f = 0; f < 8; ++f)
      gload16(gS + (size_t)f * 24576 + ko, lD + f * 512);
    __syncthreads();

    bf16x8 af[4], bf[8];
#pragma unroll
    for (int i = 0; i < 4; ++i)
      af[i] = *(const bf16x8*)(ldsA + (wave * 4 + i) * 512 + lane * 8);
#pragma unroll
    for (int n = 0; n < 8; ++n)
      bf[n] = *(const bf16x8*)(ldsB + n * 512 + lane * 8);
#pragma unroll
    for (int mi = 0; mi < 4; ++mi)
#pragma unroll
      for (int ni = 0; ni < 8; ++ni)
        acc[mi][ni] = __builtin_amdgcn_mfma_f32_16x16x32_bf16(af[mi], bf[ni], acc[mi][ni], 0, 0, 0);
    __syncthreads();
  }

  // fused LSTM epilogue: two 64-col gate groups per wave (g = 0,1)
  const int q4 = (lane >> 4) << 2;
#pragma unroll
  for (int g = 0; g < 2; ++g) {
    const int colbase = bn + g * 64;
    const int jj = (colbase >> 6) * 16 + (lane & 15);
    const int cb = colbase + (lane & 15);
    const float bI = bias[cb];
    const float bF = bias[cb + 16];
    const float bG = bias[cb + 32];
    const float bO = bias[cb + 48];
    const size_t kpart = (size_t)(16 + (jj >> 5)) * 512 + ((jj & 31) >> 3) * 128 + (jj & 7);
#pragma unroll
    for (int mi = 0; mi < 4; ++mi) {
      const size_t rowbase = (size_t)(((bm + wm) >> 4) + mi) * 24576 + kpart;
#pragma unroll
      for (int r = 0; r < 4; ++r) {
        const int b = bm + wm + mi * 16 + q4 + r;
        float ig = sigf(acc[mi][g * 4 + 0][r] + bI);
        float fg = sigf(acc[mi][g * 4 + 1][r] + bF);
        float gg = tanhfast(acc[mi][g * 4 + 2][r] + bG);
        float og = sigf(acc[mi][g * 4 + 3][r] + bO);
        size_t cidx = (size_t)b * HID + jj;
        float cn = fg * cbuf[cidx] + ig * gg;
        cbuf[cidx] = cn;
        hout[rowbase + (q4 + r) * 8] = f2bf(og * tanhfast(cn));
      }
    }
  }
}

// ---------------------------------------------------------------------------
// fcin DIRECT-REGISTER GEMM — UNCHANGED from R9/R11.
// ---------------------------------------------------------------------------
__global__ __launch_bounds__(256) void fcin_direct(
    const ushort_t* __restrict__ Xf, const ushort_t* __restrict__ Bw,
    const float* __restrict__ bias, ushort_t* __restrict__ hout,
    const float* __restrict__ bout, float* __restrict__ outp, int t) {
  const int tid = threadIdx.x;
  const int lane = tid & 63;
  const int wave = tid >> 6;
  const int bid = blockIdx.x;                    // 288, %8==0
  const int swz = (bid & 7) * 36 + (bid >> 3);   // bijective XCD swizzle
  const int wt = swz * 4 + wave;                 // 0..1151
  const int n_idx = wt >> 7;                     // 0..8
  const int m_idx = wt & 127;

  const ushort_t* pA0 = Xf + (((size_t)(m_idx * 2 + 0) * 48 + 16) << 9) + lane * 8;
  const ushort_t* pA1 = Xf + (((size_t)(m_idx * 2 + 1) * 48 + 16) << 9) + lane * 8;
  const ushort_t* pB0 = Bw + (((size_t)(n_idx * 4 + 0) * 32) << 9) + lane * 8;
  const ushort_t* pB1 = Bw + (((size_t)(n_idx * 4 + 1) * 32) << 9) + lane * 8;
  const ushort_t* pB2 = Bw + (((size_t)(n_idx * 4 + 2) * 32) << 9) + lane * 8;
  const ushort_t* pB3 = Bw + (((size_t)(n_idx * 4 + 3) * 32) << 9) + lane * 8;

  f32x4 acc[2][4] = {};
  bf16x8 aC0, aC1, bC[4], aN0, aN1, bN[4];

  aC0 = *(const bf16x8*)(pA0);
  aC1 = *(const bf16x8*)(pA1);
  bC[0] = *(const bf16x8*)(pB0);
  bC[1] = *(const bf16x8*)(pB1);
  bC[2] = *(const bf16x8*)(pB2);
  bC[3] = *(const bf16x8*)(pB3);

#pragma unroll 2
  for (int kp = 0; kp < 16; ++kp) {
    const int o1 = (2 * kp + 1) << 9;
    aN0 = *(const bf16x8*)(pA0 + o1);
    aN1 = *(const bf16x8*)(pA1 + o1);
    bN[0] = *(const bf16x8*)(pB0 + o1);
    bN[1] = *(const bf16x8*)(pB1 + o1);
    bN[2] = *(const bf16x8*)(pB2 + o1);
    bN[3] = *(const bf16x8*)(pB3 + o1);
#pragma unroll
    for (int ni = 0; ni < 4; ++ni) {
      acc[0][ni] = __builtin_amdgcn_mfma_f32_16x16x32_bf16(aC0, bC[ni], acc[0][ni], 0, 0, 0);
      acc[1][ni] = __builtin_amdgcn_mfma_f32_16x16x32_bf16(aC1, bC[ni], acc[1][ni], 0, 0, 0);
    }
    if (kp < 15) {
      const int o2 = (2 * kp + 2) << 9;
      aC0 = *(const bf16x8*)(pA0 + o2);
      aC1 = *(const bf16x8*)(pA1 + o2);
      bC[0] = *(const bf16x8*)(pB0 + o2);
      bC[1] = *(const bf16x8*)(pB1 + o2);
      bC[2] = *(const bf16x8*)(pB2 + o2);
      bC[3] = *(const bf16x8*)(pB3 + o2);
    }
#pragma unroll
    for (int ni = 0; ni < 4; ++ni) {
      acc[0][ni] = __builtin_amdgcn_mfma_f32_16x16x32_bf16(aN0, bN[ni], acc[0][ni], 0, 0, 0);
      acc[1][ni] = __builtin_amdgcn_mfma_f32_16x16x32_bf16(aN1, bN[ni], acc[1][ni], 0, 0, 0);
    }
  }

  const int q4 = (lane >> 4) << 2;
  if (n_idx < 8) {
#pragma unroll
    for (int mi = 0; mi < 2; ++mi) {
      const size_t rowbase = (size_t)(m_idx * 2 + mi) * 24576;
#pragma unroll
      for (int ni = 0; ni < 4; ++ni) {
        const int n = n_idx * 64 + ni * 16 + (lane & 15);
        const float bb = bias[n];
        const size_t kpart = (size_t)(n >> 5) * 512 + ((n & 31) >> 3) * 128 + (n & 7);
#pragma unroll
        for (int r = 0; r < 4; ++r) {
          float v = fmaxf(acc[mi][ni][r] + bb, 0.f);
          hout[rowbase + kpart + (q4 + r) * 8] = f2bf(v);
        }
      }
    }
  } else {
    const float b0 = bout[0], b1 = bout[1];
#pragma unroll
    for (int mi = 0; mi < 2; ++mi) {
#pragma unroll
      for (int r = 0; r < 4; ++r) {
        float raw = acc[mi][0][r];
        float partner = __shfl_xor(raw, 1);
        if ((lane & 15) == 0) {
          float l0 = raw + b0;
          float l1 = partner + b1;
          float m = fmaxf(l0, l1);
          float e0 = __expf(l0 - m), e1 = __expf(l1 - m);
          float inv = 1.f / (e0 + e1);
          const int row = m_idx * 32 + mi * 16 + q4 + r;
          float* o = outp + (size_t)row * (NDAYS * NOUT) + t * NOUT;
          o[0] = e0 * inv;
          o[1] = e1 * inv;
        }
      }
    }
  }
}

extern "C" void kernel_launch(void* const* d_in, const int* in_sizes, int n_in, void* d_out,
                              int out_size, void* d_ws, size_t ws_size, hipStream_t stream) {
  const float* hx = (const float*)d_in[0];
  const float* cx = (const float*)d_in[1];
  const float* Wih = (const float*)d_in[2];
  const float* Whh = (const float*)d_in[3];
  const float* bih = (const float*)d_in[4];
  const float* bhh = (const float*)d_in[5];
  const float* Wfcin = (const float*)d_in[6];
  const float* bfcin = (const float*)d_in[7];
  const float* Wfcout = (const float*)d_in[8];
  const float* bfcout = (const float*)d_in[9];
  const float* Wspan = (const float*)d_in[10];
  const float* bspan = (const float*)d_in[11];
  float* out = (float*)d_out;

  char* ws = (char*)d_ws;
  ushort_t* Wgf = (ushort_t*)(ws);               // 4096*1536*2 = 12582912
  ushort_t* Wfc2 = (ushort_t*)(ws + 12582912);   // 576*1024*2  =  1179648
  float* bg = (float*)(ws + 13762560);           // 4096*4      =    16384
  ushort_t* XA = (ushort_t*)(ws + 13778944);     // 12582912
  ushort_t* XB = (ushort_t*)(ws + 26361856);     // 12582912
  float* cbuf = (float*)(ws + 38944768);         // 16777216 -> total 55721984 B

  prep_gates_w<<<3072, 256, 0, stream>>>(Wih, Whh, bih, bhh, Wgf, bg);
  prep_fcin_w<<<288, 256, 0, stream>>>(Wfcin, Wfcout, Wfc2);
  init_x<<<3072, 256, 0, stream>>>(hx, XA);
  hipMemcpyAsync(cbuf, cx, (size_t)BSZ * HID * 4, hipMemcpyDeviceToDevice, stream);
  span_kernel<<<(BSZ * NSPAN) / 256, 256, 0, stream>>>(hx, Wspan, bspan, out);

  float* outp = out + BSZ * NSPAN;
  for (int t = 0; t < NDAYS; ++t) {
    ushort_t* Xin = (t & 1) ? XB : XA;
    ushort_t* Xout = (t & 1) ? XA : XB;
    gates128_kernel<<<dim3(32, 32), 128, 0, stream>>>(Xin, Wgf, bg, cbuf, Xout);
    if (t < NDAYS - 1) {
      fcin_direct<<<288, 256, 0, stream>>>(Xout, Wfc2, bfcin, Xout, bfcout, outp, t);
    } else {
      fcout_kernel<<<BSZ / 4, 256, 0, stream>>>(Xout, Wfcout, bfcout, outp, t);
    }
  }
}

// Round 13
// 1493.080 us; speedup vs baseline: 1.0333x; 1.0333x over previous
//
#include <hip/hip_runtime.h>

typedef __bf16 bf16x8 __attribute__((ext_vector_type(8)));
typedef float f32x4 __attribute__((ext_vector_type(4)));
typedef unsigned short ushort_t;
typedef unsigned short u16x8 __attribute__((ext_vector_type(8)));

#define BSZ 4096
#define HID 1024
#define INPD 512
#define NSPAN 8
#define NOUT 2
#define NDAYS 20
#define XLD 1536  // X = [inp(512) | h(1024)] K-dim

// Frag-order layout: element (row, k) of a [R][K] bf16 matrix lives at
//   ((row>>4)*(K/32) + (k>>5))*512 + ((k&31)>>3)*128 + (row&15)*8 + (k&7)
// each 16x32 MFMA fragment is 1KB contiguous = exact mfma_16x16x32 operand map.

__device__ __forceinline__ ushort_t f2bf(float f) {
  union { float f; unsigned u; } v; v.f = f;
  unsigned r = v.u + 0x7FFFu + ((v.u >> 16) & 1u);
  return (ushort_t)(r >> 16);
}
__device__ __forceinline__ float bf2f(ushort_t b) {
  union { unsigned u; float f; } v; v.u = ((unsigned)b) << 16;
  return v.f;
}
__device__ __forceinline__ float sigf(float x) { return 1.f / (1.f + __expf(-x)); }
__device__ __forceinline__ float tanhfast(float x) { return 2.f / (1.f + __expf(-2.f * x)) - 1.f; }

__device__ __forceinline__ void gload16(const void* g, void* l) {
  __builtin_amdgcn_global_load_lds((const __attribute__((address_space(1))) void*)g,
                                   (__attribute__((address_space(3))) void*)l, 16, 0, 0);
}

// ---------------------------------------------------------------------------
// Wg prep -> frag-order. Gate-reordered row r_perm = (j/16)*64 + gate*16 + (j%16).
// ---------------------------------------------------------------------------
__global__ void prep_gates_w(const float* __restrict__ Wih, const float* __restrict__ Whh,
                             const float* __restrict__ bih, const float* __restrict__ bhh,
                             ushort_t* __restrict__ Wgf, float* __restrict__ bg) {
  int gid = blockIdx.x * 256 + threadIdx.x;
  int rb = gid / 3072;           // 48*64
  int rem = gid - rb * 3072;
  int kk = rem >> 6;
  int li = rem & 63;
  int rp = rb * 16 + (li & 15);
  int kb = kk * 32 + ((li >> 4) << 3);
  int g = (rp >> 4) & 3;
  int j = (rp >> 6) * 16 + (rp & 15);
  int src = g * HID + j;
  const float* s = (kb < INPD) ? (Wih + (size_t)src * INPD + kb)
                               : (Whh + (size_t)src * HID + (kb - INPD));
  u16x8 o;
#pragma unroll
  for (int e = 0; e < 8; ++e) o[e] = f2bf(s[e]);
  *(u16x8*)(Wgf + (size_t)gid * 8) = o;
  if (kk == 0 && li < 16) bg[rp] = bih[src] + bhh[src];
}

// Wfc2 prep -> frag-order [576][1024]: rows 0..511 = Wfcin, 512..513 = Wfcout,
// 514..575 = 0.  gid over 576*1024/8 = 73728 -> 288 blocks.
__global__ void prep_fcin_w(const float* __restrict__ W, const float* __restrict__ Wout,
                            ushort_t* __restrict__ Wf) {
  int gid = blockIdx.x * 256 + threadIdx.x;
  int rb = gid / 2048;           // 32*64
  int rem = gid - rb * 2048;
  int kk = rem >> 6;
  int li = rem & 63;
  int row = rb * 16 + (li & 15);
  int kb = kk * 32 + ((li >> 4) << 3);
  u16x8 o;
  if (row < 512) {
    const float* s = W + (size_t)row * HID + kb;
#pragma unroll
    for (int e = 0; e < 8; ++e) o[e] = f2bf(s[e]);
  } else if (row < 514) {
    const float* s = Wout + (size_t)(row - 512) * HID + kb;
#pragma unroll
    for (int e = 0; e < 8; ++e) o[e] = f2bf(s[e]);
  } else {
#pragma unroll
    for (int e = 0; e < 8; ++e) o[e] = 0;
  }
  *(u16x8*)(Wf + (size_t)gid * 8) = o;
}

// X init (frag-order): inp part zeros, h part = bf16(hx)
__global__ void init_x(const float* __restrict__ hx, ushort_t* __restrict__ Xf) {
  int gid = blockIdx.x * 256 + threadIdx.x;
  int rb = gid / 3072;
  int rem = gid - rb * 3072;
  int kk = rem >> 6;
  int li = rem & 63;
  int row = rb * 16 + (li & 15);
  int kb = kk * 32 + ((li >> 4) << 3);
  u16x8 o;
  if (kb < INPD) {
#pragma unroll
    for (int e = 0; e < 8; ++e) o[e] = 0;
  } else {
    const float* s = hx + (size_t)row * HID + (kb - INPD);
#pragma unroll
    for (int e = 0; e < 8; ++e) o[e] = f2bf(s[e]);
  }
  *(u16x8*)(Xf + (size_t)gid * 8) = o;
}

// num_spans = softmax(hx @ W_span.T + b_span), fp32.
// v2: one wave per batch row — hx row read ONCE (64B/lane), Wspan (32KB)
// L1-resident, butterfly-reduce 8 accumulators across the wave.
__global__ void span_kernel(const float* __restrict__ hx, const float* __restrict__ Wspan,
                            const float* __restrict__ bspan, float* __restrict__ out) {
  const int lane = threadIdx.x & 63;
  const int wave = threadIdx.x >> 6;
  const int b = blockIdx.x * 4 + wave;
  const float4* hr = (const float4*)(hx + (size_t)b * HID + lane * 16);
  float4 h0 = hr[0], h1 = hr[1], h2 = hr[2], h3 = hr[3];
  float acc[NSPAN];
#pragma unroll
  for (int o = 0; o < NSPAN; ++o) {
    const float4* wr = (const float4*)(Wspan + (size_t)o * HID + lane * 16);
    float4 w0 = wr[0], w1 = wr[1], w2 = wr[2], w3 = wr[3];
    acc[o] = h0.x * w0.x + h0.y * w0.y + h0.z * w0.z + h0.w * w0.w
           + h1.x * w1.x + h1.y * w1.y + h1.z * w1.z + h1.w * w1.w
           + h2.x * w2.x + h2.y * w2.y + h2.z * w2.z + h2.w * w2.w
           + h3.x * w3.x + h3.y * w3.y + h3.z * w3.z + h3.w * w3.w;
  }
#pragma unroll
  for (int s = 1; s < 64; s <<= 1)
#pragma unroll
    for (int o = 0; o < NSPAN; ++o) acc[o] += __shfl_xor(acc[o], s);
  // all lanes now hold all 8 sums; lanes 0..7 write
  float m = -1e30f;
#pragma unroll
  for (int o = 0; o < NSPAN; ++o) {
    acc[o] += bspan[o];
    m = fmaxf(m, acc[o]);
  }
  float ssum = 0.f;
#pragma unroll
  for (int o = 0; o < NSPAN; ++o) {
    acc[o] = __expf(acc[o] - m);
    ssum += acc[o];
  }
  if (lane < NSPAN) out[(size_t)b * NSPAN + lane] = acc[lane] / ssum;
}

// standalone fcout (only t = NDAYS-1), reads frag-order X
__global__ void fcout_kernel(const ushort_t* __restrict__ Xf, const float* __restrict__ W,
                             const float* __restrict__ bvec, float* __restrict__ outp, int t) {
  const int lane = threadIdx.x & 63;
  const int wave = threadIdx.x >> 6;
  const int b = blockIdx.x * 4 + wave;
  const int rb = b >> 4, r = b & 15;
  const int kk = 16 + (lane >> 1);
  const int ss = (lane & 1) * 2;
  const size_t base = ((size_t)rb * 48 + kk) * 512 + (ss * 16 + r) * 8;
  u16x8 h0 = *(const u16x8*)(Xf + base);
  u16x8 h1 = *(const u16x8*)(Xf + base + 128);
  const float* w0 = W + lane * 16;
  const float* w1 = W + HID + lane * 16;
  float l0 = 0.f, l1 = 0.f;
#pragma unroll
  for (int j = 0; j < 8; ++j) {
    float ha = bf2f(h0[j]);
    l0 += ha * w0[j];
    l1 += ha * w1[j];
    float hb = bf2f(h1[j]);
    l0 += hb * w0[j + 8];
    l1 += hb * w1[j + 8];
  }
#pragma unroll
  for (int s = 32; s > 0; s >>= 1) {
    l0 += __shfl_xor(l0, s);
    l1 += __shfl_xor(l1, s);
  }
  if (lane == 0) {
    l0 += bvec[0];
    l1 += bvec[1];
    float m = fmaxf(l0, l1);
    float e0 = __expf(l0 - m), e1 = __expf(l1 - m);
    float inv = 1.f / (e0 + e1);
    float* o = outp + (size_t)b * (NDAYS * NOUT) + t * NOUT;
    o[0] = e0 * inv;
    o[1] = e1 * inv;
  }
}

// ---------------------------------------------------------------------------
// Gates GEMM: 128x128 / BK=32 / 4-wave, frag-order operands, frag-linear LDS.
// EXACT R9/R11 version (59.5 us = 866 TF). This is the proven optimum of the
// structure family: BK=64 (R10), 2-wave-wide (R12), 8-phase 256^2 (R3/R4/R8)
// all regressed — TLP at 4 waves/SIMD is the binding latency-hiding resource.
// ---------------------------------------------------------------------------
__global__ void gates128_kernel(const ushort_t* __restrict__ A,
                                const ushort_t* __restrict__ B,
                                const float* __restrict__ bias, float* __restrict__ cbuf,
                                ushort_t* __restrict__ hout) {
  __shared__ __align__(16) ushort_t ldsA[8 * 512];
  __shared__ __align__(16) ushort_t ldsB[8 * 512];
  const int tid = threadIdx.x;
  const int lane = tid & 63;
  const int wave = tid >> 6;

  int bid = blockIdx.y * gridDim.x + blockIdx.x;
  int nwg = gridDim.x * gridDim.y;
  int cpx = nwg >> 3;
  int swz = (bid & 7) * cpx + (bid >> 3);
  int bx = swz % gridDim.x;
  int by = swz / gridDim.x;
  const int bm = bx * 128;
  const int bn = by * 128;
  const int wm = (wave >> 1) * 64;
  const int wn = (wave & 1) * 64;

  f32x4 acc[4][4] = {};

  const int f0 = wave * 2, f1 = wave * 2 + 1;
  const ushort_t* gA0 = A + ((size_t)((bm >> 4) + f0) * 48) * 512 + lane * 8;
  const ushort_t* gA1 = A + ((size_t)((bm >> 4) + f1) * 48) * 512 + lane * 8;
  const ushort_t* gB0 = B + ((size_t)((bn >> 4) + f0) * 48) * 512 + lane * 8;
  const ushort_t* gB1 = B + ((size_t)((bn >> 4) + f1) * 48) * 512 + lane * 8;

  for (int kk = 0; kk < 48; ++kk) {
    const int ko = kk * 512;
    gload16(gA0 + ko, ldsA + f0 * 512);
    gload16(gA1 + ko, ldsA + f1 * 512);
    gload16(gB0 + ko, ldsB + f0 * 512);
    gload16(gB1 + ko, ldsB + f1 * 512);
    __syncthreads();

    bf16x8 af[4], bf[4];
#pragma unroll
    for (int i = 0; i < 4; ++i) {
      af[i] = *(const bf16x8*)(ldsA + ((wm >> 4) + i) * 512 + lane * 8);
      bf[i] = *(const bf16x8*)(ldsB + ((wn >> 4) + i) * 512 + lane * 8);
    }
#pragma unroll
    for (int mi = 0; mi < 4; ++mi)
#pragma unroll
      for (int ni = 0; ni < 4; ++ni)
        acc[mi][ni] = __builtin_amdgcn_mfma_f32_16x16x32_bf16(af[mi], bf[ni], acc[mi][ni], 0, 0, 0);
    __syncthreads();
  }

  const int colbase = bn + wn;
  const int jj = (colbase >> 6) * 16 + (lane & 15);
  const int cb = colbase + (lane & 15);
  const float bI = bias[cb];
  const float bF = bias[cb + 16];
  const float bG = bias[cb + 32];
  const float bO = bias[cb + 48];
  const size_t kpart = (size_t)(16 + (jj >> 5)) * 512 + ((jj & 31) >> 3) * 128 + (jj & 7);
  const int q4 = (lane >> 4) << 2;
#pragma unroll
  for (int mi = 0; mi < 4; ++mi) {
    const size_t rowbase = (size_t)(((bm + wm) >> 4) + mi) * 24576 + kpart;
#pragma unroll
    for (int r = 0; r < 4; ++r) {
      const int b = bm + wm + mi * 16 + q4 + r;
      float ig = sigf(acc[mi][0][r] + bI);
      float fg = sigf(acc[mi][1][r] + bF);
      float gg = tanhfast(acc[mi][2][r] + bG);
      float og = sigf(acc[mi][3][r] + bO);
      size_t cidx = (size_t)b * HID + jj;
      float cn = fg * cbuf[cidx] + ig * gg;
      cbuf[cidx] = cn;
      hout[rowbase + (q4 + r) * 8] = f2bf(og * tanhfast(cn));
    }
  }
}

// ---------------------------------------------------------------------------
// fcin DIRECT-REGISTER GEMM — UNCHANGED from R9/R11.
// ---------------------------------------------------------------------------
__global__ __launch_bounds__(256) void fcin_direct(
    const ushort_t* __restrict__ Xf, const ushort_t* __restrict__ Bw,
    const float* __restrict__ bias, ushort_t* __restrict__ hout,
    const float* __restrict__ bout, float* __restrict__ outp, int t) {
  const int tid = threadIdx.x;
  const int lane = tid & 63;
  const int wave = tid >> 6;
  const int bid = blockIdx.x;                    // 288, %8==0
  const int swz = (bid & 7) * 36 + (bid >> 3);   // bijective XCD swizzle
  const int wt = swz * 4 + wave;                 // 0..1151
  const int n_idx = wt >> 7;                     // 0..8
  const int m_idx = wt & 127;

  const ushort_t* pA0 = Xf + (((size_t)(m_idx * 2 + 0) * 48 + 16) << 9) + lane * 8;
  const ushort_t* pA1 = Xf + (((size_t)(m_idx * 2 + 1) * 48 + 16) << 9) + lane * 8;
  const ushort_t* pB0 = Bw + (((size_t)(n_idx * 4 + 0) * 32) << 9) + lane * 8;
  const ushort_t* pB1 = Bw + (((size_t)(n_idx * 4 + 1) * 32) << 9) + lane * 8;
  const ushort_t* pB2 = Bw + (((size_t)(n_idx * 4 + 2) * 32) << 9) + lane * 8;
  const ushort_t* pB3 = Bw + (((size_t)(n_idx * 4 + 3) * 32) << 9) + lane * 8;

  f32x4 acc[2][4] = {};
  bf16x8 aC0, aC1, bC[4], aN0, aN1, bN[4];

  aC0 = *(const bf16x8*)(pA0);
  aC1 = *(const bf16x8*)(pA1);
  bC[0] = *(const bf16x8*)(pB0);
  bC[1] = *(const bf16x8*)(pB1);
  bC[2] = *(const bf16x8*)(pB2);
  bC[3] = *(const bf16x8*)(pB3);

#pragma unroll 2
  for (int kp = 0; kp < 16; ++kp) {
    const int o1 = (2 * kp + 1) << 9;
    aN0 = *(const bf16x8*)(pA0 + o1);
    aN1 = *(const bf16x8*)(pA1 + o1);
    bN[0] = *(const bf16x8*)(pB0 + o1);
    bN[1] = *(const bf16x8*)(pB1 + o1);
    bN[2] = *(const bf16x8*)(pB2 + o1);
    bN[3] = *(const bf16x8*)(pB3 + o1);
#pragma unroll
    for (int ni = 0; ni < 4; ++ni) {
      acc[0][ni] = __builtin_amdgcn_mfma_f32_16x16x32_bf16(aC0, bC[ni], acc[0][ni], 0, 0, 0);
      acc[1][ni] = __builtin_amdgcn_mfma_f32_16x16x32_bf16(aC1, bC[ni], acc[1][ni], 0, 0, 0);
    }
    if (kp < 15) {
      const int o2 = (2 * kp + 2) << 9;
      aC0 = *(const bf16x8*)(pA0 + o2);
      aC1 = *(const bf16x8*)(pA1 + o2);
      bC[0] = *(const bf16x8*)(pB0 + o2);
      bC[1] = *(const bf16x8*)(pB1 + o2);
      bC[2] = *(const bf16x8*)(pB2 + o2);
      bC[3] = *(const bf16x8*)(pB3 + o2);
    }
#pragma unroll
    for (int ni = 0; ni < 4; ++ni) {
      acc[0][ni] = __builtin_amdgcn_mfma_f32_16x16x32_bf16(aN0, bN[ni], acc[0][ni], 0, 0, 0);
      acc[1][ni] = __builtin_amdgcn_mfma_f32_16x16x32_bf16(aN1, bN[ni], acc[1][ni], 0, 0, 0);
    }
  }

  const int q4 = (lane >> 4) << 2;
  if (n_idx < 8) {
#pragma unroll
    for (int mi = 0; mi < 2; ++mi) {
      const size_t rowbase = (size_t)(m_idx * 2 + mi) * 24576;
#pragma unroll
      for (int ni = 0; ni < 4; ++ni) {
        const int n = n_idx * 64 + ni * 16 + (lane & 15);
        const float bb = bias[n];
        const size_t kpart = (size_t)(n >> 5) * 512 + ((n & 31) >> 3) * 128 + (n & 7);
#pragma unroll
        for (int r = 0; r < 4; ++r) {
          float v = fmaxf(acc[mi][ni][r] + bb, 0.f);
          hout[rowbase + kpart + (q4 + r) * 8] = f2bf(v);
        }
      }
    }
  } else {
    const float b0 = bout[0], b1 = bout[1];
#pragma unroll
    for (int mi = 0; mi < 2; ++mi) {
#pragma unroll
      for (int r = 0; r < 4; ++r) {
        float raw = acc[mi][0][r];
        float partner = __shfl_xor(raw, 1);
        if ((lane & 15) == 0) {
          float l0 = raw + b0;
          float l1 = partner + b1;
          float m = fmaxf(l0, l1);
          float e0 = __expf(l0 - m), e1 = __expf(l1 - m);
          float inv = 1.f / (e0 + e1);
          const int row = m_idx * 32 + mi * 16 + q4 + r;
          float* o = outp + (size_t)row * (NDAYS * NOUT) + t * NOUT;
          o[0] = e0 * inv;
          o[1] = e1 * inv;
        }
      }
    }
  }
}

extern "C" void kernel_launch(void* const* d_in, const int* in_sizes, int n_in, void* d_out,
                              int out_size, void* d_ws, size_t ws_size, hipStream_t stream) {
  const float* hx = (const float*)d_in[0];
  const float* cx = (const float*)d_in[1];
  const float* Wih = (const float*)d_in[2];
  const float* Whh = (const float*)d_in[3];
  const float* bih = (const float*)d_in[4];
  const float* bhh = (const float*)d_in[5];
  const float* Wfcin = (const float*)d_in[6];
  const float* bfcin = (const float*)d_in[7];
  const float* Wfcout = (const float*)d_in[8];
  const float* bfcout = (const float*)d_in[9];
  const float* Wspan = (const float*)d_in[10];
  const float* bspan = (const float*)d_in[11];
  float* out = (float*)d_out;

  char* ws = (char*)d_ws;
  ushort_t* Wgf = (ushort_t*)(ws);               // 4096*1536*2 = 12582912
  ushort_t* Wfc2 = (ushort_t*)(ws + 12582912);   // 576*1024*2  =  1179648
  float* bg = (float*)(ws + 13762560);           // 4096*4      =    16384
  ushort_t* XA = (ushort_t*)(ws + 13778944);     // 12582912
  ushort_t* XB = (ushort_t*)(ws + 26361856);     // 12582912
  float* cbuf = (float*)(ws + 38944768);         // 16777216 -> total 55721984 B

  prep_gates_w<<<3072, 256, 0, stream>>>(Wih, Whh, bih, bhh, Wgf, bg);
  prep_fcin_w<<<288, 256, 0, stream>>>(Wfcin, Wfcout, Wfc2);
  init_x<<<3072, 256, 0, stream>>>(hx, XA);
  hipMemcpyAsync(cbuf, cx, (size_t)BSZ * HID * 4, hipMemcpyDeviceToDevice, stream);
  span_kernel<<<BSZ / 4, 256, 0, stream>>>(hx, Wspan, bspan, out);

  float* outp = out + BSZ * NSPAN;
  for (int t = 0; t < NDAYS; ++t) {
    ushort_t* Xin = (t & 1) ? XB : XA;
    ushort_t* Xout = (t & 1) ? XA : XB;
    gates128_kernel<<<dim3(32, 32), 256, 0, stream>>>(Xin, Wgf, bg, cbuf, Xout);
    if (t < NDAYS - 1) {
      fcin_direct<<<288, 256, 0, stream>>>(Xout, Wfc2, bfcin, Xout, bfcout, outp, t);
    } else {
      fcout_kernel<<<BSZ / 4, 256, 0, stream>>>(Xout, Wfcout, bfcout, outp, t);
    }
  }
}